// Round 8
// baseline (496.848 us; speedup 1.0000x reference)
//
#include <hip/hip_runtime.h>
#include <hip/hip_bf16.h>
#include <math.h>

// Problem constants
#define LSEQ 2048
#define DMODEL 1024
#define DINNER 2048
#define DSTATE 16
#define DCONV 4
#define DTRANK 64
#define RPROJ 96   // DTRANK + 2*DSTATE

// Chunked-scan decomposition
#define CHUNK 16
#define NCHUNK (LSEQ / CHUNK)   // 128

#define XSPLIT 4                // split-K factor for x_proj

typedef __attribute__((ext_vector_type(8))) short bf16x8;
typedef __attribute__((ext_vector_type(4))) float f32x4;

__device__ __forceinline__ float softplusf(float x) {
    return (x > 20.f) ? x : log1pf(__expf(x));
}
__device__ __forceinline__ float siluf(float x) {
    return x / (1.f + __expf(-x));
}
// f32 -> bf16 RTNE
__device__ __forceinline__ short f2bf(float f) {
    union { float f; unsigned u; } v; v.f = f;
    unsigned r = v.u + 0x7FFFu + ((v.u >> 16) & 1u);
    return (short)(r >> 16);
}
// bf16 -> f32
__device__ __forceinline__ float bf2f(short h) {
    union { unsigned u; float f; } v;
    v.u = ((unsigned)(unsigned short)h) << 16;
    return v.f;
}

__device__ __forceinline__ void cvt8(const float* __restrict__ s,
                                     short* __restrict__ d, int i) {
    const float4 a = *(const float4*)(s + i);
    const float4 b = *(const float4*)(s + i + 4);
    alignas(16) short h[8];
    h[0] = f2bf(a.x); h[1] = f2bf(a.y); h[2] = f2bf(a.z); h[3] = f2bf(a.w);
    h[4] = f2bf(b.x); h[5] = f2bf(b.y); h[6] = f2bf(b.z); h[7] = f2bf(b.w);
    *(uint4*)(d + i) = *(const uint4*)h;
}

// ---------------- fused f32 -> bf16 convert of all 4 weight tensors -------
__global__ __launch_bounds__(256) void cvt_weights(
    const float* __restrict__ s0, short* __restrict__ d0, int n0,
    const float* __restrict__ s1, short* __restrict__ d1, int n1,
    const float* __restrict__ s2, short* __restrict__ d2, int n2,
    const float* __restrict__ s3, short* __restrict__ d3, int n3)
{
    int i = (blockIdx.x * 256 + threadIdx.x) * 8;
    if (i < n0) { cvt8(s0, d0, i); return; }
    i -= n0;
    if (i < n1) { cvt8(s1, d1, i); return; }
    i -= n1;
    if (i < n2) { cvt8(s2, d2, i); return; }
    i -= n2;
    if (i < n3) { cvt8(s3, d3, i); return; }
}

// ---------------- LayerNorm: one block per row; f32 or bf16 out ----------
__global__ __launch_bounds__(256) void ln_kernel(
    const float* __restrict__ x, const float* __restrict__ w,
    const float* __restrict__ b, float* __restrict__ outf,
    short* __restrict__ outb)
{
    __shared__ float s1[256], s2[256];
    const int row = blockIdx.x;
    const int tid = threadIdx.x;
    const float* xr = x + (size_t)row * DMODEL;
    float v[4];
    float s = 0.f, sq = 0.f;
#pragma unroll
    for (int k = 0; k < 4; k++) {
        v[k] = xr[k * 256 + tid];
        s += v[k];
        sq += v[k] * v[k];
    }
    s1[tid] = s; s2[tid] = sq;
    __syncthreads();
    for (int off = 128; off > 0; off >>= 1) {
        if (tid < off) { s1[tid] += s1[tid + off]; s2[tid] += s2[tid + off]; }
        __syncthreads();
    }
    const float mu = s1[0] * (1.f / DMODEL);
    const float var = s2[0] * (1.f / DMODEL) - mu * mu;
    const float rstd = rsqrtf(var + 1e-5f);
#pragma unroll
    for (int k = 0; k < 4; k++) {
        const int i = k * 256 + tid;
        const float o = (v[k] - mu) * rstd * w[i] + b[i];
        if (outf) outf[(size_t)row * DMODEL + i] = o;
        if (outb) outb[(size_t)row * DMODEL + i] = f2bf(o);
    }
}

// ------- bf16 MFMA NT GEMM, (32*MI) x (32*NJ) tile, double-buffered LDS ---
// C[M,N] = A[M,K] * W[N,K]^T, K per z-slice (blockIdx.z offsets A/W by z*K,
// C by z*csplit). 2x2 waves per block. Double-buffered K-loop: stage k+1
// into the other LDS buffer BEFORE computing on the current one; ONE
// barrier per K-iter (was two) and the load latency overlaps MFMA+ds_read.
// XOR swizzle: row r chunk c stored at phys chunk c ^ ((r>>1)&3) -> 2-way
// bank aliasing (free) for the quarter-wave ds_read_b128 pattern.
// MODE 0: f32 store (csplit)   MODE 2: f32 (. + resid)
// MODE 3: bf16 store           MODE 5: bf16 softplus(.+bias[n])
template<int MI, int NJ, int MODE>
__global__ __launch_bounds__(256) void gemm_mfma(
    const short* __restrict__ A, int lda,   // [M,lda] bf16
    const short* __restrict__ W, int ldw,   // [N,ldw] bf16
    float* __restrict__ Cf, short* __restrict__ Cb, int ldc,
    int M, int N, int K,
    const float* __restrict__ bias,
    const float* __restrict__ resid,
    size_t csplit)
{
    constexpr int BM = 32 * MI;
    constexpr int BN = 32 * NJ;
    constexpr int AISS = BM / 64;          // A staging issues per buffer
    constexpr int WISS = BN / 64;          // W staging issues per buffer
    __shared__ alignas(16) short As[2][BM * 32];
    __shared__ alignas(16) short Ws[2][BN * 32];

    const int tid = threadIdx.x;
    const int lane = tid & 63;
    const int w = tid >> 6;
    const int wr = w >> 1, wc = w & 1;     // 2x2 waves
    const int row0 = blockIdx.y * BM;
    const int col0 = blockIdx.x * BN;
    const int kbeg = blockIdx.z * K;

    const int srow = tid >> 2;                              // staging row (0..63)
    const int skch = ((tid & 3) ^ ((srow >> 1) & 3)) * 8;   // swizzled k chunk

    f32x4 acc[MI][NJ];
#pragma unroll
    for (int i = 0; i < MI; i++)
#pragma unroll
        for (int j = 0; j < NJ; j++) acc[i][j] = (f32x4)0.f;

    const int lrow = lane & 15;
    const int q = lane >> 4;               // logical chunk wanted by this lane
    const int NIT = K / 32;

    auto stage = [&](int p, int kt) {
#pragma unroll
        for (int j = 0; j < AISS; j++) {
            const short* gp = A + (size_t)(row0 + j * 64 + srow) * lda + kt + skch;
            __builtin_amdgcn_global_load_lds(
                (const __attribute__((address_space(1))) void*)gp,
                (__attribute__((address_space(3))) void*)(&As[p][j * 2048 + tid * 8]),
                16, 0, 0);
        }
#pragma unroll
        for (int j = 0; j < WISS; j++) {
            const int wrow = col0 + j * 64 + srow;
            if (wrow < N) {
                const short* gp = W + (size_t)wrow * ldw + kt + skch;
                __builtin_amdgcn_global_load_lds(
                    (const __attribute__((address_space(1))) void*)gp,
                    (__attribute__((address_space(3))) void*)(&Ws[p][j * 2048 + tid * 8]),
                    16, 0, 0);
            }
        }
    };

    stage(0, kbeg);
    __syncthreads();
    for (int it = 0; it < NIT; ++it) {
        const int p = it & 1;
        // prefetch next K-tile into the other buffer (overlaps compute below)
        if (it + 1 < NIT) stage(p ^ 1, kbeg + (it + 1) * 32);

        bf16x8 af[MI], bfr[NJ];
#pragma unroll
        for (int i = 0; i < MI; i++) {
            const int R = wr * (16 * MI) + i * 16 + lrow;
            af[i] = *(const bf16x8*)&As[p][R * 32 + ((q ^ ((R >> 1) & 3)) * 8)];
        }
#pragma unroll
        for (int j = 0; j < NJ; j++) {
            const int R = wc * (16 * NJ) + j * 16 + lrow;
            bfr[j] = *(const bf16x8*)&Ws[p][R * 32 + ((q ^ ((R >> 1) & 3)) * 8)];
        }
#pragma unroll
        for (int i = 0; i < MI; i++)
#pragma unroll
            for (int j = 0; j < NJ; j++)
                acc[i][j] = __builtin_amdgcn_mfma_f32_16x16x32_bf16(
                    af[i], bfr[j], acc[i][j], 0, 0, 0);
        __syncthreads();
    }

    if (MODE == 0 && csplit) Cf += blockIdx.z * csplit;

    // epilogue: C/D layout col=lane&15, row=(lane>>4)*4+reg
    const int rbase = row0 + wr * (16 * MI);
    const int cbase = col0 + wc * (16 * NJ);
#pragma unroll
    for (int i = 0; i < MI; i++) {
#pragma unroll
        for (int j = 0; j < NJ; j++) {
            const int gcol = cbase + j * 16 + lrow;
            if (gcol < N) {
#pragma unroll
                for (int r = 0; r < 4; r++) {
                    const int grow = rbase + i * 16 + (lane >> 4) * 4 + r;
                    float v = acc[i][j][r];
                    if (MODE == 2) v += resid[(size_t)grow * ldc + gcol];
                    if (MODE == 5) v = softplusf(v + bias[gcol]);
                    if (MODE == 3 || MODE == 5) {
                        Cb[(size_t)grow * ldc + gcol] = f2bf(v);
                    } else {
                        Cf[(size_t)grow * ldc + gcol] = v;
                    }
                }
            }
        }
    }
}

// ---------------- x_proj split-K combine: dbl = sum of partials ----------
__global__ __launch_bounds__(256) void combine_xproj(
    const float* __restrict__ part,   // [XSPLIT][LSEQ*RPROJ]
    float* __restrict__ dbl, short* __restrict__ dblb)
{
    const int i = (blockIdx.x * 256 + threadIdx.x) * 4;
    const int S = LSEQ * RPROJ;
    float4 v = *(const float4*)(part + i);
#pragma unroll
    for (int s = 1; s < XSPLIT; s++) {
        const float4 p = *(const float4*)(part + s * S + i);
        v.x += p.x; v.y += p.y; v.z += p.z; v.w += p.w;
    }
    *(float4*)(dbl + i) = v;
    alignas(8) short h[4] = {f2bf(v.x), f2bf(v.y), f2bf(v.z), f2bf(v.w)};
    *(unsigned long long*)(dblb + i) = *(const unsigned long long*)h;
}

// ---------------- Causal depthwise conv (k=4) + bias + silu --------------
// 8 channels per thread, bf16x8 vector loads/stores.
__global__ __launch_bounds__(256) void conv_silu_kernel(
    const short* __restrict__ xzb, const float* __restrict__ cw,
    const float* __restrict__ cb, short* __restrict__ xcb)
{
    const int g = blockIdx.x * 256 + threadIdx.x;   // over L * DINNER/8
    const int t = g >> 8;             // DINNER/8 = 256 groups per t
    const int c0 = (g & 255) * 8;
    float acc[8];
#pragma unroll
    for (int j = 0; j < 8; j++) acc[j] = cb[c0 + j];
#pragma unroll
    for (int k = 0; k < DCONV; k++) {
        const int tt = t - (DCONV - 1) + k;
        if (tt >= 0) {
            const bf16x8 v = *(const bf16x8*)(xzb + (size_t)tt * (2 * DINNER) + c0);
#pragma unroll
            for (int j = 0; j < 8; j++)
                acc[j] += bf2f(v[j]) * cw[(c0 + j) * DCONV + k];
        }
    }
    alignas(16) short h[8];
#pragma unroll
    for (int j = 0; j < 8; j++) h[j] = f2bf(siluf(acc[j]));
    *(uint4*)(xcb + (size_t)t * DINNER + c0) = *(const uint4*)h;
}

// ============ Chunked selective scan ============
// pass1: chunk-local scan from h=0; explicit next-t prefetch hides latency.
__global__ __launch_bounds__(256) void scan_pass1(
    const short* __restrict__ dtb,   // [L, DINNER] bf16
    const short* __restrict__ xcb,   // [L, DINNER] bf16
    const float* __restrict__ dbl,   // [L, RPROJ] f32
    const float* __restrict__ A_log,
    float* __restrict__ S,           // [NCHUNK][DSTATE][DINNER]
    float* __restrict__ sumdt)       // [NCHUNK][DINNER]
{
    const int e = blockIdx.x * 256 + threadIdx.x;
    const int c = blockIdx.y;
    float a[DSTATE];
#pragma unroll
    for (int n = 0; n < DSTATE; n++) a[n] = -__expf(A_log[(size_t)e * DSTATE + n]);
    float h[DSTATE];
#pragma unroll
    for (int n = 0; n < DSTATE; n++) h[n] = 0.f;
    float sd = 0.f;

    __shared__ float sBC[CHUNK][32];
    for (int i = threadIdx.x; i < CHUNK * 32; i += 256) {
        const int tl = i >> 5, j = i & 31;
        sBC[tl][j] = dbl[(size_t)(c * CHUNK + tl) * RPROJ + DTRANK + j];
    }
    __syncthreads();

    const size_t rb = (size_t)c * CHUNK * DINNER + e;
    short dt_c = dtb[rb], xc_c = xcb[rb];
#pragma unroll
    for (int tl = 0; tl < CHUNK; tl++) {
        short dt_n = 0, xc_n = 0;
        if (tl + 1 < CHUNK) {
            dt_n = dtb[rb + (size_t)(tl + 1) * DINNER];
            xc_n = xcb[rb + (size_t)(tl + 1) * DINNER];
        }
        const float dtv = bf2f(dt_c);
        const float du = dtv * bf2f(xc_c);
        sd += dtv;
#pragma unroll
        for (int n = 0; n < DSTATE; n++) {
            const float dA = __expf(dtv * a[n]);
            h[n] = dA * h[n] + du * sBC[tl][n];
        }
        dt_c = dt_n; xc_c = xc_n;
    }
    sumdt[(size_t)c * DINNER + e] = sd;
#pragma unroll
    for (int n = 0; n < DSTATE; n++)
        S[((size_t)c * DSTATE + n) * DINNER + e] = h[n];
}

// pass2: sequential combine over chunks; rewrite S in place with carry-IN.
// Prefetch next chunk's S/sumdt to decouple loads from the exp/fma chain.
__global__ __launch_bounds__(256) void scan_pass2(
    const float* __restrict__ A_log,
    const float* __restrict__ sumdt,
    float* __restrict__ S)
{
    const int idx = blockIdx.x * 256 + threadIdx.x;
    const int e = idx & (DINNER - 1);
    const int n = idx >> 11;
    const float a = -__expf(A_log[(size_t)e * DSTATE + n]);
    const size_t base = (size_t)n * DINNER + e;
    const size_t cstr = (size_t)DSTATE * DINNER;
    float H = 0.f;
    float sc = S[base];
    float sd = sumdt[e];
    for (int c = 0; c < NCHUNK; c++) {
        float sc_n = 0.f, sd_n = 0.f;
        if (c + 1 < NCHUNK) {
            sc_n = S[base + (size_t)(c + 1) * cstr];
            sd_n = sumdt[(size_t)(c + 1) * DINNER + e];
        }
        S[base + (size_t)c * cstr] = H;
        H = __expf(a * sd) * H + sc;
        sc = sc_n; sd = sd_n;
    }
}

// pass3: seeded chunk-local scan -> gated y (bf16 for out_proj)
__global__ __launch_bounds__(256) void scan_pass3(
    const short* __restrict__ dtb,
    const short* __restrict__ xcb,
    const float* __restrict__ dbl,
    const short* __restrict__ xzb,   // z at cols DINNER.. (bf16)
    const float* __restrict__ A_log,
    const float* __restrict__ Dp,
    const float* __restrict__ S,
    short* __restrict__ yb)
{
    const int e = blockIdx.x * 256 + threadIdx.x;
    const int c = blockIdx.y;
    float a[DSTATE];
#pragma unroll
    for (int n = 0; n < DSTATE; n++) a[n] = -__expf(A_log[(size_t)e * DSTATE + n]);
    float h[DSTATE];
#pragma unroll
    for (int n = 0; n < DSTATE; n++)
        h[n] = S[((size_t)c * DSTATE + n) * DINNER + e];
    const float dskip = Dp[e];

    __shared__ float sBC[CHUNK][32];
    for (int i = threadIdx.x; i < CHUNK * 32; i += 256) {
        const int tl = i >> 5, j = i & 31;
        sBC[tl][j] = dbl[(size_t)(c * CHUNK + tl) * RPROJ + DTRANK + j];
    }
    __syncthreads();

    const size_t rb = (size_t)c * CHUNK * DINNER + e;
    const size_t zb = (size_t)c * CHUNK * (2 * DINNER) + DINNER + e;
    short dt_c = dtb[rb], xc_c = xcb[rb], z_c = xzb[zb];
#pragma unroll
    for (int tl = 0; tl < CHUNK; tl++) {
        short dt_n = 0, xc_n = 0, z_n = 0;
        if (tl + 1 < CHUNK) {
            dt_n = dtb[rb + (size_t)(tl + 1) * DINNER];
            xc_n = xcb[rb + (size_t)(tl + 1) * DINNER];
            z_n = xzb[zb + (size_t)(tl + 1) * (2 * DINNER)];
        }
        const float dtv = bf2f(dt_c);
        const float xcv = bf2f(xc_c);
        const float du = dtv * xcv;
        float yv = 0.f;
#pragma unroll
        for (int n = 0; n < DSTATE; n++) {
            const float dA = __expf(dtv * a[n]);
            h[n] = dA * h[n] + du * sBC[tl][n];
            yv += h[n] * sBC[tl][16 + n];
        }
        yv = (yv + xcv * dskip) * siluf(bf2f(z_c));
        yb[rb + (size_t)tl * DINNER] = f2bf(yv);
        dt_c = dt_n; xc_c = xc_n; z_c = z_n;
    }
}

extern "C" void kernel_launch(void* const* d_in, const int* in_sizes, int n_in,
                              void* d_out, int out_size, void* d_ws, size_t ws_size,
                              hipStream_t stream) {
    const float* x_in   = (const float*)d_in[0];
    const float* ln_w   = (const float*)d_in[1];
    const float* ln_b   = (const float*)d_in[2];
    const float* in_w   = (const float*)d_in[3];
    const float* conv_w = (const float*)d_in[4];
    const float* conv_b = (const float*)d_in[5];
    const float* xp_w   = (const float*)d_in[6];
    const float* dtp_w  = (const float*)d_in[7];
    const float* dtp_b  = (const float*)d_in[8];
    const float* A_log  = (const float*)d_in[9];
    const float* D_skip = (const float*)d_in[10];
    const float* out_w  = (const float*)d_in[11];
    const float* nf_w   = (const float*)d_in[12];
    const float* nf_b   = (const float*)d_in[13];
    float* out = (float*)d_out;

    float* w = (float*)d_ws;
    float* buf_x = w; w += (size_t)LSEQ * DMODEL;              // residual stream (f32)
    float* dbl   = w; w += (size_t)LSEQ * RPROJ;               // x_proj out (f32)
    float* xpart = w; w += (size_t)XSPLIT * LSEQ * RPROJ;      // x_proj split-K partials
    float* Sbuf  = w; w += (size_t)NCHUNK * DSTATE * DINNER;   // chunk summaries
    float* sumdt = w; w += (size_t)NCHUNK * DINNER;
    // bf16 buffers (sized in float units, 2 shorts per float)
    short* h_bf    = (short*)w; w += (size_t)LSEQ * DMODEL / 2;
    short* xz_bf   = (short*)w; w += (size_t)LSEQ * 2 * DINNER / 2;
    short* xc_bf   = (short*)w; w += (size_t)LSEQ * DINNER / 2;
    short* dt_bf   = (short*)w; w += (size_t)LSEQ * DINNER / 2;
    short* y_bf    = (short*)w; w += (size_t)LSEQ * DINNER / 2;
    short* dbl_bf  = (short*)w; w += (size_t)LSEQ * RPROJ / 2 + 1;
    short* in_w_bf  = (short*)w; w += (size_t)2 * (2 * DINNER) * DMODEL / 2;
    short* xp_w_bf  = (short*)w; w += (size_t)2 * RPROJ * DINNER / 2;
    short* dtp_w_bf = (short*)w; w += (size_t)2 * DINNER * DTRANK / 2;
    short* out_w_bf = (short*)w; w += (size_t)2 * DMODEL * DINNER / 2;

    // fused weight conversion (all layers, all 4 tensors, one dispatch)
    {
        const int n1 = 2 * (2 * DINNER) * DMODEL;   // 8388608
        const int n2 = 2 * RPROJ * DINNER;          // 393216
        const int n3 = 2 * DMODEL * DINNER;         // 4194304
        const int n4 = 2 * DINNER * DTRANK;         // 262144
        const int total = n1 + n2 + n3 + n4;        // 13238272
        cvt_weights<<<dim3(total / (256 * 8)), dim3(256), 0, stream>>>(
            in_w, in_w_bf, n1, xp_w, xp_w_bf, n2,
            out_w, out_w_bf, n3, dtp_w, dtp_w_bf, n4);
    }

    for (int layer = 0; layer < 2; layer++) {
        const float* resid_src = (layer == 0) ? x_in : buf_x;
        // 1. LayerNorm -> bf16
        ln_kernel<<<dim3(LSEQ), dim3(256), 0, stream>>>(
            resid_src, ln_w + layer * DMODEL, ln_b + layer * DMODEL,
            nullptr, h_bf);
        // 2. in_proj (MFMA 64x128 dbuf, bf16 out): xz_bf[L,4096] = h * in_w^T
        gemm_mfma<2, 4, 3><<<dim3((2 * DINNER) / 128, LSEQ / 64), dim3(256), 0, stream>>>(
            h_bf, DMODEL, in_w_bf + (size_t)layer * 2 * DINNER * DMODEL, DMODEL,
            nullptr, xz_bf, 2 * DINNER, LSEQ, 2 * DINNER, DMODEL, nullptr, nullptr, 0);
        // 3. conv + silu -> bf16 (vectorized)
        conv_silu_kernel<<<dim3((LSEQ * DINNER / 8) / 256), dim3(256), 0, stream>>>(
            xz_bf, conv_w + (size_t)layer * DINNER * DCONV, conv_b + layer * DINNER,
            xc_bf);
        // 4. x_proj (MFMA 64x64 dbuf, split-K=4 -> partials) + combine
        gemm_mfma<2, 2, 0><<<dim3(2, LSEQ / 64, XSPLIT), dim3(256), 0, stream>>>(
            xc_bf, DINNER, xp_w_bf + (size_t)layer * RPROJ * DINNER, DINNER,
            xpart, nullptr, RPROJ, LSEQ, RPROJ, DINNER / XSPLIT, nullptr, nullptr,
            (size_t)LSEQ * RPROJ);
        combine_xproj<<<dim3((LSEQ * RPROJ / 4) / 256), dim3(256), 0, stream>>>(
            xpart, dbl, dbl_bf);
        // 5. dt_proj (MFMA 64x128 dbuf, softplus+bias -> bf16): dt_bf, K=64
        gemm_mfma<2, 4, 5><<<dim3(DINNER / 128, LSEQ / 64), dim3(256), 0, stream>>>(
            dbl_bf, RPROJ, dtp_w_bf + (size_t)layer * DINNER * DTRANK, DTRANK,
            nullptr, dt_bf, DINNER, LSEQ, DINNER, DTRANK,
            dtp_b + layer * DINNER, nullptr, 0);
        // 6. chunked selective scan (+ skip + z-gate) -> y_bf
        const float* Al = A_log + (size_t)layer * DINNER * DSTATE;
        scan_pass1<<<dim3(DINNER / 256, NCHUNK), dim3(256), 0, stream>>>(
            dt_bf, xc_bf, dbl, Al, Sbuf, sumdt);
        scan_pass2<<<dim3((DINNER * DSTATE) / 256), dim3(256), 0, stream>>>(
            Al, sumdt, Sbuf);
        scan_pass3<<<dim3(DINNER / 256, NCHUNK), dim3(256), 0, stream>>>(
            dt_bf, xc_bf, dbl, xz_bf, Al, D_skip + layer * DINNER, Sbuf, y_bf);
        // 7. out_proj (MFMA 64x64 dbuf) + residual -> buf_x f32
        gemm_mfma<2, 2, 2><<<dim3(DMODEL / 64, LSEQ / 64), dim3(256), 0, stream>>>(
            y_bf, DINNER, out_w_bf + (size_t)layer * DMODEL * DINNER, DINNER,
            buf_x, nullptr, DMODEL, LSEQ, DMODEL, DINNER, nullptr, resid_src, 0);
    }
    // final LayerNorm -> d_out (f32)
    ln_kernel<<<dim3(LSEQ), dim3(256), 0, stream>>>(buf_x, nf_w, nf_b, out, nullptr);
}